// Round 1
// baseline (316.682 us; speedup 1.0000x reference)
//
#include <hip/hip_runtime.h>
#include <hip/hip_bf16.h>

// PatchMask: out[b,c,h,w] = x[b,c,h,w] * keep_mask[b, h/16, w/16]
// x: fp32 [64,3,512,512]  (50,331,648 elems, 201 MB)
// keep_mask: bool->int32 [64,32,32]  (65,536 elems)
// Memory-bound elementwise pass: float4 per thread, one mask lookup per float4
// (4 consecutive w-pixels are always inside one 16-wide patch).

#define W_DIM 512
#define H_DIM 512
#define CH 3
#define PATCH 16

__global__ __launch_bounds__(256) void PatchMask_kernel(
    const float4* __restrict__ x,
    const int* __restrict__ mask,
    float4* __restrict__ out,
    int n4)
{
    int i = blockIdx.x * blockDim.x + threadIdx.x;
    if (i >= n4) return;

    int e = i << 2;                 // element index (max ~50.3M, fits int32)
    int w = e & (W_DIM - 1);        // 512 = 2^9
    int h = (e >> 9) & (H_DIM - 1);
    int bc = e >> 18;               // b*3 + c  (512*512 = 2^18)
    int b = bc / CH;                // compiler emits magic-mul

    // mask is [B, 32, 32]
    int mi = (b << 10) + ((h >> 4) << 5) + (w >> 4);

    float4 v = x[i];
    if (mask[mi] == 0) {
        v.x = 0.f; v.y = 0.f; v.z = 0.f; v.w = 0.f;
    }
    out[i] = v;
}

extern "C" void kernel_launch(void* const* d_in, const int* in_sizes, int n_in,
                              void* d_out, int out_size, void* d_ws, size_t ws_size,
                              hipStream_t stream) {
    const float4* x   = (const float4*)d_in[0];
    const int* mask   = (const int*)d_in[1];
    float4* out       = (float4*)d_out;

    int n4 = out_size >> 2;                      // 12,582,912
    int block = 256;
    int grid = (n4 + block - 1) / block;         // 49,152

    PatchMask_kernel<<<grid, block, 0, stream>>>(x, mask, out, n4);
}